// Round 8
// baseline (1279.835 us; speedup 1.0000x reference)
//
#include <hip/hip_runtime.h>
#include <hip/hip_bf16.h>

// Problem constants (fixed by reference)
#define V_NODES 50000
#define N_EDGES 500000
#define H_DIM 128
#define NCLUST 10
#define BN_EPS 1e-5f
#define NB_SCAN ((V_NODES + 255) / 256)   // 196
#define GT_ROWS 32
#define GT_NTILES ((V_NODES + GT_ROWS - 1) / GT_ROWS)  // 1563

// ---------------------------------------------------------------------------
// x[v] = emb[signal[v]]   (float4-vectorized gather)
// ---------------------------------------------------------------------------
__global__ __launch_bounds__(256) void embed_kernel(const int* __restrict__ signal,
                                                    const float* __restrict__ emb,
                                                    float* __restrict__ x) {
    int idx = blockIdx.x * 256 + threadIdx.x;       // over V*32 float4s
    if (idx >= V_NODES * 32) return;
    int v = idx >> 5;
    int q = idx & 31;
    int s = signal[v];
    ((float4*)x)[idx] = ((const float4*)emb)[s * 32 + q];
}

// ---------------------------------------------------------------------------
// CSR build (by destination node). deg must be zeroed beforehand.
// ---------------------------------------------------------------------------
__global__ __launch_bounds__(256) void hist_kernel(const int* __restrict__ end_idx,
                                                   int* __restrict__ deg) {
    int e = blockIdx.x * 256 + threadIdx.x;
    if (e >= N_EDGES) return;
    atomicAdd(&deg[end_idx[e]], 1);
}

__global__ __launch_bounds__(256) void reduce_block_kernel(const int* __restrict__ deg,
                                                           int* __restrict__ blockSums) {
    __shared__ int sh[256];
    int t = threadIdx.x;
    int i = blockIdx.x * 256 + t;
    sh[t] = (i < V_NODES) ? deg[i] : 0;
    __syncthreads();
    for (int s = 128; s > 0; s >>= 1) {
        if (t < s) sh[t] += sh[t + s];
        __syncthreads();
    }
    if (t == 0) blockSums[blockIdx.x] = sh[0];
}

__global__ void scan_sums_kernel(const int* __restrict__ blockSums,
                                 int* __restrict__ blockOffs) {
    if (threadIdx.x == 0) {
        int run = 0;
        for (int i = 0; i < NB_SCAN; ++i) { blockOffs[i] = run; run += blockSums[i]; }
    }
}

// writes BOTH offsets and cursor (avoids a D2D memcpy in the launch)
__global__ __launch_bounds__(256) void scan_block_kernel(const int* __restrict__ deg,
                                                         const int* __restrict__ blockOffs,
                                                         int* __restrict__ offsets,
                                                         int* __restrict__ cursor) {
    __shared__ int sh[256];
    int t = threadIdx.x;
    int i = blockIdx.x * 256 + t;
    int v = (i < V_NODES) ? deg[i] : 0;
    sh[t] = v;
    __syncthreads();
    int run = v;
    for (int ofs = 1; ofs < 256; ofs <<= 1) {
        int add = (t >= ofs) ? sh[t - ofs] : 0;
        __syncthreads();
        run += add;
        sh[t] = run;
        __syncthreads();
    }
    if (i < V_NODES) {
        int o = run - v + blockOffs[blockIdx.x];
        offsets[i] = o;
        cursor[i] = o;
    }
}

// edge_src[p] = start node, grouped by dst
__global__ __launch_bounds__(256) void scatter_kernel(const int* __restrict__ start_idx,
                                                      const int* __restrict__ end_idx,
                                                      int* __restrict__ cursor,
                                                      int* __restrict__ edge_src) {
    int e = blockIdx.x * 256 + threadIdx.x;
    if (e >= N_EDGES) return;
    int d = end_idx[e];
    int p = atomicAdd(&cursor[d], 1);
    edge_src[p] = start_idx[e];
}

// ---------------------------------------------------------------------------
// Transpose all 18 weight matrices once: WT[m][k][j] = W[m][j][k].
// grid (16, 18): 16 32x32 tiles per 128x128 matrix.
// ---------------------------------------------------------------------------
struct TransArgs { const float* src[18]; };

__global__ __launch_bounds__(256) void transpose_w(TransArgs ta, float* __restrict__ dst) {
    __shared__ float tile[32][33];
    int m = blockIdx.y;
    const float* __restrict__ src = ta.src[m];
    float* __restrict__ d = dst + (size_t)m * 16384;
    int tx = threadIdx.x & 31;
    int ty = threadIdx.x >> 5;          // 0..7
    int bj = (blockIdx.x & 3) * 32;     // source row block (j)
    int bk = (blockIdx.x >> 2) * 32;    // source col block (k)
#pragma unroll
    for (int r = 0; r < 32; r += 8)
        tile[ty + r][tx] = src[(bj + ty + r) * 128 + bk + tx];
    __syncthreads();
#pragma unroll
    for (int r = 0; r < 32; r += 8)
        d[(bk + ty + r) * 128 + bj + tx] = tile[tx][ty + r];
}

// ---------------------------------------------------------------------------
// X-resident tiled multi-weight GEMM: out_w = X @ W_w^T (+ bias_w).
// Block owns a 32-row X tile, staged ONCE into padded LDS (xs[32][132]) and
// reused for all nw*2 (weight, col-half) quanta; the 32 KB half-weight
// wsh[128k][64j] streams through LDS per quantum (W total is L2-resident).
// 21 barriers/block, zero global loads in the inner loop. 48.9 KB LDS ->
// 3 blocks/CU. Thread tile 4 rows x 2 cols: per k4: 4x ds_read_b128 (A,
// 2-way broadcast-aliased = free) + 4x b64 (B, 2-way = free) + 32 FMA.
// X global traffic: 25.6 MB once (vs 256 MB in the persistent-W variant).
// ---------------------------------------------------------------------------
struct GemmArgs {
    const float* WT[5];
    const float* bias[5];
    float*       out[5];
    int          ldc2[5];   // output row stride in float2 units (64=dense, 128=packed)
    int          nw;
};

__global__ __launch_bounds__(256, 3) void gemm_tile(const float* __restrict__ X,
                                                    GemmArgs args) {
    __shared__ float xs[GT_ROWS][132];   // 16.9 KB, +4 pad: rows on distinct banks
    __shared__ float wsh[128 * 64];      // 32 KB half-weight [k][j]
    const int t  = threadIdx.x;
    const int cg = t & 31;               // cols cg*2, cg*2+1 (of 64)
    const int rg = t >> 5;               // rows rg*4 .. rg*4+3 (of 32)
    const int row0 = blockIdx.x * GT_ROWS;

    // ---- stage X tile once: 32 rows x 32 float4 = 1024 float4, 4/thread ----
#pragma unroll
    for (int i = 0; i < 4; ++i) {
        int idx = t + i * 256;           // 0..1023
        int r = idx >> 5;
        int q = idx & 31;
        int rr = row0 + r;
        float4 v = ((const float4*)X)[(size_t)(rr < V_NODES ? rr : V_NODES - 1) * 32 + q];
        *(float4*)&xs[r][q * 4] = v;
    }

    bool ok[4];
#pragma unroll
    for (int i = 0; i < 4; ++i) ok[i] = (row0 + rg * 4 + i) < V_NODES;

    const int nq = args.nw * 2;
    for (int wch = 0; wch < nq; ++wch) {
        const int w  = wch >> 1;
        const int ch = wch & 1;

        // ---- stage half-weight wsh[k][j] = WT[w][k][ch*64+j], 8 float4/thr
        const float4* __restrict__ wsrc = (const float4*)args.WT[w] + ch * 16;
        __syncthreads();                 // previous quantum done reading wsh
                                         // (also covers initial xs stage)
#pragma unroll
        for (int i = 0; i < 8; ++i) {
            int idx = t + i * 256;       // 0..2047
            int k  = idx >> 4;
            int jq = idx & 15;
            ((float4*)wsh)[(k << 4) + jq] = wsrc[k * 32 + jq];
        }
        __syncthreads();

        // ---- inner loop: all operands in LDS ----
        float acc[4][2];
#pragma unroll
        for (int i = 0; i < 4; ++i) { acc[i][0] = 0.f; acc[i][1] = 0.f; }

#pragma unroll 4
        for (int k4 = 0; k4 < 32; ++k4) {
            float4 a[4];
#pragma unroll
            for (int i = 0; i < 4; ++i)
                a[i] = *(const float4*)&xs[rg * 4 + i][k4 * 4];
            float2 b[4];
#pragma unroll
            for (int e = 0; e < 4; ++e)
                b[e] = *(const float2*)&wsh[(k4 * 4 + e) * 64 + cg * 2];
#pragma unroll
            for (int e = 0; e < 4; ++e) {
#pragma unroll
                for (int i = 0; i < 4; ++i) {
                    float av = ((const float*)&a[i])[e];
                    acc[i][0] += av * b[e].x;
                    acc[i][1] += av * b[e].y;
                }
            }
        }

        // ---- epilogue: bias + float2 store (coalesced across cg) ----
        const float* bias = args.bias[w];
        float b0 = bias ? bias[ch * 64 + cg * 2 + 0] : 0.f;
        float b1 = bias ? bias[ch * 64 + cg * 2 + 1] : 0.f;
        float2* O = (float2*)args.out[w];
        const int ldc2 = args.ldc2[w];
#pragma unroll
        for (int i = 0; i < 4; ++i) {
            if (ok[i]) {
                float2 o = make_float2(acc[i][0] + b0, acc[i][1] + b1);
                O[(size_t)(row0 + rg * 4 + i) * ldc2 + ch * 32 + cg] = o;
            }
        }
    }
}

// ---------------------------------------------------------------------------
// Gather-style aggregation (no atomics), packed source operand.
// P[v] = [ Vjx[v] (128 f32) | Ujx[v] (128 f32) ]  -> one contiguous 1 KB
// region per gathered source node. agg[d] prefilled with Uix[d] + bu.
//   acc = agg[d]; for each in-edge (s -> d):
//     acc += sigmoid(Vix[d] + Vjx[s] + bv) * Ujx[s]
// Block: 256 threads = 8 nodes x 32 lanes (float4 per lane).
// ---------------------------------------------------------------------------
__global__ __launch_bounds__(256) void agg_kernel(const float* __restrict__ Vix,
                                                  const float* __restrict__ P,
                                                  const float* __restrict__ bv,
                                                  const int* __restrict__ offsets,
                                                  const int* __restrict__ deg,
                                                  const int* __restrict__ edge_src,
                                                  float* __restrict__ agg) {
    int t = threadIdx.x;
    int node = blockIdx.x * 8 + (t >> 5);
    int q = t & 31;
    if (node >= V_NODES) return;

    float4 vi  = ((const float4*)Vix)[node * 32 + q];
    float4 bvv = ((const float4*)bv)[q];
    float4 acc = ((const float4*)agg)[node * 32 + q];   // Uix + bu prefill

    int off = offsets[node];
    int dg  = deg[node];
#pragma unroll 2
    for (int i = 0; i < dg; ++i) {
        int s = edge_src[off + i];                      // broadcast across 32 lanes
        const float4* Pr = (const float4*)P + (size_t)s * 64;
        float4 vj = Pr[q];
        float4 uj = Pr[32 + q];
        float g0 = 1.f / (1.f + __expf(-(vi.x + vj.x + bvv.x)));
        float g1 = 1.f / (1.f + __expf(-(vi.y + vj.y + bvv.y)));
        float g2 = 1.f / (1.f + __expf(-(vi.z + vj.z + bvv.z)));
        float g3 = 1.f / (1.f + __expf(-(vi.w + vj.w + bvv.w)));
        acc.x += g0 * uj.x;
        acc.y += g1 * uj.y;
        acc.z += g2 * uj.z;
        acc.w += g3 * uj.w;
    }
    ((float4*)agg)[node * 32 + q] = acc;
}

// ---------------------------------------------------------------------------
// Per-column sum / sum-of-squares over V rows -> stats[0..127]=sum,
// stats[128..255]=sumsq. stats must be zeroed beforehand.
// ---------------------------------------------------------------------------
__global__ __launch_bounds__(256) void bn_stats_kernel(const float* __restrict__ h,
                                                       float* __restrict__ stats) {
    __shared__ float s1[256], s2[256];
    int t = threadIdx.x;
    int j = t & 127;
    int half = t >> 7;
    float sum = 0.f, ss = 0.f;
    for (int r = blockIdx.x * 2 + half; r < V_NODES; r += gridDim.x * 2) {
        float v = h[r * 128 + j];
        sum += v; ss += v * v;
    }
    s1[t] = sum; s2[t] = ss;
    __syncthreads();
    if (t < 128) {
        sum = s1[t] + s1[t + 128];
        ss = s2[t] + s2[t + 128];
        atomicAdd(&stats[j], sum);
        atomicAdd(&stats[128 + j], ss);
    }
}

// ---------------------------------------------------------------------------
// x2 = relu(g*(h-mean)*rsqrt(var+eps)+b)
// ---------------------------------------------------------------------------
__global__ __launch_bounds__(256) void norm_relu_kernel(const float* __restrict__ h,
                                                        const float* __restrict__ stats,
                                                        const float* __restrict__ g,
                                                        const float* __restrict__ b,
                                                        float* __restrict__ out) {
    int idx = blockIdx.x * 256 + threadIdx.x;       // over V*32
    if (idx >= V_NODES * 32) return;
    int q = idx & 31;
    float4 hv = ((const float4*)h)[idx];
    float hvv[4] = {hv.x, hv.y, hv.z, hv.w};
    const float invV = 1.f / (float)V_NODES;
    float o[4];
#pragma unroll
    for (int c = 0; c < 4; ++c) {
        int j = q * 4 + c;
        float m = stats[j] * invV;
        float var = stats[128 + j] * invV - m * m;
        float sc = g[j] * rsqrtf(var + BN_EPS);
        float val = (hvv[c] - m) * sc + b[j];
        o[c] = fmaxf(val, 0.f);
    }
    ((float4*)out)[idx] = make_float4(o[0], o[1], o[2], o[3]);
}

// x3 = relu(bn(h) + rx)
__global__ __launch_bounds__(256) void norm_res_relu_kernel(const float* __restrict__ h,
                                                            const float* __restrict__ stats,
                                                            const float* __restrict__ g,
                                                            const float* __restrict__ b,
                                                            const float* __restrict__ rx,
                                                            float* __restrict__ out) {
    int idx = blockIdx.x * 256 + threadIdx.x;
    if (idx >= V_NODES * 32) return;
    int q = idx & 31;
    float4 hv = ((const float4*)h)[idx];
    float4 rv = ((const float4*)rx)[idx];
    float hvv[4] = {hv.x, hv.y, hv.z, hv.w};
    float rvv[4] = {rv.x, rv.y, rv.z, rv.w};
    const float invV = 1.f / (float)V_NODES;
    float o[4];
#pragma unroll
    for (int c = 0; c < 4; ++c) {
        int j = q * 4 + c;
        float m = stats[j] * invV;
        float var = stats[128 + j] * invV - m * m;
        float sc = g[j] * rsqrtf(var + BN_EPS);
        float val = (hvv[c] - m) * sc + b[j] + rvv[c];
        o[c] = fmaxf(val, 0.f);
    }
    ((float4*)out)[idx] = make_float4(o[0], o[1], o[2], o[3]);
}

// ---------------------------------------------------------------------------
// out[v,k] = sum_h x[v,h]*fc_w[k,h] + fc_b[k]    (k=0..9)
// ---------------------------------------------------------------------------
__global__ __launch_bounds__(256) void fc_kernel(const float* __restrict__ X,
                                                 const float* __restrict__ fw,
                                                 const float* __restrict__ fb,
                                                 float* __restrict__ out) {
    __shared__ float fwsh[NCLUST][132];
    __shared__ float fbsh[NCLUST];
    int t = threadIdx.x;
    for (int i = t; i < NCLUST * 128; i += 256) fwsh[i >> 7][i & 127] = fw[i];
    if (t < NCLUST) fbsh[t] = fb[t];
    __syncthreads();
    int rl = t >> 5;
    int q = t & 31;
    int r = blockIdx.x * 8 + rl;
    float4 xv = make_float4(0.f, 0.f, 0.f, 0.f);
    if (r < V_NODES) xv = ((const float4*)X)[r * 32 + q];
    float p[NCLUST];
#pragma unroll
    for (int k = 0; k < NCLUST; ++k) {
        float4 wv = *(const float4*)&fwsh[k][q * 4];
        p[k] = xv.x * wv.x + xv.y * wv.y + xv.z * wv.z + xv.w * wv.w;
    }
#pragma unroll
    for (int off = 16; off > 0; off >>= 1)
#pragma unroll
        for (int k = 0; k < NCLUST; ++k) p[k] += __shfl_down(p[k], off, 32);
    if (q == 0 && r < V_NODES) {
#pragma unroll
        for (int k = 0; k < NCLUST; ++k) out[r * NCLUST + k] = p[k] + fbsh[k];
    }
}

// ---------------------------------------------------------------------------
extern "C" void kernel_launch(void* const* d_in, const int* in_sizes, int n_in,
                              void* d_out, int out_size, void* d_ws, size_t ws_size,
                              hipStream_t stream) {
    (void)in_sizes; (void)n_in; (void)out_size; (void)ws_size;
    const int*   signal    = (const int*)d_in[0];
    const int*   start_idx = (const int*)d_in[1];
    const int*   end_idx   = (const int*)d_in[2];
    const float* emb       = (const float*)d_in[3];
    const float* Ui1 = (const float*)d_in[4];
    const float* Uj1 = (const float*)d_in[5];
    const float* Vi1 = (const float*)d_in[6];
    const float* Vj1 = (const float*)d_in[7];
    const float* Ui2 = (const float*)d_in[8];
    const float* Uj2 = (const float*)d_in[9];
    const float* Vi2 = (const float*)d_in[10];
    const float* Vj2 = (const float*)d_in[11];
    const float* Rw  = (const float*)d_in[12];
    const float* bu1 = (const float*)d_in[13];
    const float* bv1 = (const float*)d_in[14];
    const float* bu2 = (const float*)d_in[15];
    const float* bv2 = (const float*)d_in[16];
    const float* bn1_g = (const float*)d_in[17];
    const float* bn2_g = (const float*)d_in[18];
    const float* bn1_b = (const float*)d_in[19];
    const float* bn2_b = (const float*)d_in[20];
    const float* fc_w  = (const float*)d_in[21];
    const float* fc_b  = (const float*)d_in[22];
    float* out = (float*)d_out;

    // workspace: X, VI, P(2*VH packed Vj|Uj), AGG, RX  = 6*VH f32,
    // + WT (18*16384), + stats, + CSR int arrays
    const size_t VH = (size_t)V_NODES * H_DIM;
    float* ws  = (float*)d_ws;
    float* X   = ws + 0 * VH;
    float* VI  = ws + 1 * VH;
    float* P   = ws + 2 * VH;   // packed [V][256]: Vjx | Ujx
    float* AGG = ws + 4 * VH;   // Uix + bu, then += gathered messages
    float* RX  = ws + 5 * VH;
    float* stats = ws + 6 * VH;                 // 4 x 256 floats
    float* WT    = stats + 4 * 256;             // 18 x 128 x 128 transposed weights
    int* ip        = (int*)(WT + 18 * 16384);
    int* deg       = ip;                        // V
    int* offsets   = ip + V_NODES;              // V
    int* cursor    = ip + 2 * V_NODES;          // V
    int* blockSums = ip + 3 * V_NODES;          // NB_SCAN
    int* blockOffs = blockSums + NB_SCAN;       // NB_SCAN
    int* edge_src  = blockOffs + NB_SCAN;       // N_EDGES

    hipMemsetAsync(stats, 0, 4 * 256 * sizeof(float), stream);
    hipMemsetAsync(deg, 0, V_NODES * sizeof(int), stream);

    const int vec_grid  = (V_NODES * 32 + 255) / 256;   // 6250
    const int edge_grid = (N_EDGES + 255) / 256;        // 1954
    const int node_grid = (V_NODES + 7) / 8;            // 6250

    // ---- transpose all 18 weight matrices once ----
    // slot order per cell c: [0]=Vi1 [1]=Vj1 [2]=Uj1 [3]=Ui1 [4]=R
    //                        [5]=Vi2 [6]=Vj2 [7]=Uj2 [8]=Ui2
    TransArgs ta;
    for (int c = 0; c < 2; ++c) {
        const int wo = c * H_DIM * H_DIM;
        ta.src[c * 9 + 0] = Vi1 + wo;
        ta.src[c * 9 + 1] = Vj1 + wo;
        ta.src[c * 9 + 2] = Uj1 + wo;
        ta.src[c * 9 + 3] = Ui1 + wo;
        ta.src[c * 9 + 4] = Rw  + wo;
        ta.src[c * 9 + 5] = Vi2 + wo;
        ta.src[c * 9 + 6] = Vj2 + wo;
        ta.src[c * 9 + 7] = Uj2 + wo;
        ta.src[c * 9 + 8] = Ui2 + wo;
    }
    transpose_w<<<dim3(16, 18), 256, 0, stream>>>(ta, WT);

    // ---- CSR build (end_idx is the same for both cells) ----
    hist_kernel<<<edge_grid, 256, 0, stream>>>(end_idx, deg);
    reduce_block_kernel<<<NB_SCAN, 256, 0, stream>>>(deg, blockSums);
    scan_sums_kernel<<<1, 64, 0, stream>>>(blockSums, blockOffs);
    scan_block_kernel<<<NB_SCAN, 256, 0, stream>>>(deg, blockOffs, offsets, cursor);
    scatter_kernel<<<edge_grid, 256, 0, stream>>>(start_idx, end_idx, cursor, edge_src);

    embed_kernel<<<vec_grid, 256, 0, stream>>>(signal, emb, X);

    for (int c = 0; c < 2; ++c) {
        const int bo = c * H_DIM;
        float* WTc = WT + (size_t)c * 9 * 16384;

        // ---- half-cell 1: Vi, Vj->P, Uj->P+128, Ui->AGG(+bu), R->RX ----
        GemmArgs g1;
        g1.WT[0] = WTc + 0 * 16384; g1.bias[0] = nullptr;  g1.out[0] = VI;      g1.ldc2[0] = 64;
        g1.WT[1] = WTc + 1 * 16384; g1.bias[1] = nullptr;  g1.out[1] = P;       g1.ldc2[1] = 128;
        g1.WT[2] = WTc + 2 * 16384; g1.bias[2] = nullptr;  g1.out[2] = P + 128; g1.ldc2[2] = 128;
        g1.WT[3] = WTc + 3 * 16384; g1.bias[3] = bu1 + bo; g1.out[3] = AGG;     g1.ldc2[3] = 64;
        g1.WT[4] = WTc + 4 * 16384; g1.bias[4] = nullptr;  g1.out[4] = RX;      g1.ldc2[4] = 64;
        g1.nw = 5;
        gemm_tile<<<GT_NTILES, 256, 0, stream>>>(X, g1);
        agg_kernel<<<node_grid, 256, 0, stream>>>(VI, P, bv1 + bo,
                                                  offsets, deg, edge_src, AGG);
        bn_stats_kernel<<<1024, 256, 0, stream>>>(AGG, stats + c * 512);
        norm_relu_kernel<<<vec_grid, 256, 0, stream>>>(AGG, stats + c * 512,
                                                       bn1_g + bo, bn1_b + bo, X);

        // ---- half-cell 2 ----
        GemmArgs g2;
        g2.WT[0] = WTc + 5 * 16384; g2.bias[0] = nullptr;  g2.out[0] = VI;      g2.ldc2[0] = 64;
        g2.WT[1] = WTc + 6 * 16384; g2.bias[1] = nullptr;  g2.out[1] = P;       g2.ldc2[1] = 128;
        g2.WT[2] = WTc + 7 * 16384; g2.bias[2] = nullptr;  g2.out[2] = P + 128; g2.ldc2[2] = 128;
        g2.WT[3] = WTc + 8 * 16384; g2.bias[3] = bu2 + bo; g2.out[3] = AGG;     g2.ldc2[3] = 64;
        g2.nw = 4;
        gemm_tile<<<GT_NTILES, 256, 0, stream>>>(X, g2);
        agg_kernel<<<node_grid, 256, 0, stream>>>(VI, P, bv2 + bo,
                                                  offsets, deg, edge_src, AGG);
        bn_stats_kernel<<<1024, 256, 0, stream>>>(AGG, stats + c * 512 + 256);
        norm_res_relu_kernel<<<vec_grid, 256, 0, stream>>>(AGG, stats + c * 512 + 256,
                                                           bn2_g + bo, bn2_b + bo,
                                                           RX, X);
    }

    fc_kernel<<<(V_NODES + 7) / 8, 256, 0, stream>>>(X, fc_w, fc_b, out);
}

// Round 9
// 1172.214 us; speedup vs baseline: 1.0918x; 1.0918x over previous
//
#include <hip/hip_runtime.h>
#include <hip/hip_bf16.h>

// Problem constants (fixed by reference)
#define V_NODES 50000
#define N_EDGES 500000
#define H_DIM 128
#define NCLUST 10
#define BN_EPS 1e-5f
#define NB_SCAN ((V_NODES + 255) / 256)   // 196
#define GB_ROWS 64
#define GB_NT ((V_NODES + GB_ROWS - 1) / GB_ROWS)   // 782

// ---------------------------------------------------------------------------
// x[v] = emb[signal[v]]   (float4-vectorized gather)
// ---------------------------------------------------------------------------
__global__ __launch_bounds__(256) void embed_kernel(const int* __restrict__ signal,
                                                    const float* __restrict__ emb,
                                                    float* __restrict__ x) {
    int idx = blockIdx.x * 256 + threadIdx.x;       // over V*32 float4s
    if (idx >= V_NODES * 32) return;
    int v = idx >> 5;
    int q = idx & 31;
    int s = signal[v];
    ((float4*)x)[idx] = ((const float4*)emb)[s * 32 + q];
}

// ---------------------------------------------------------------------------
// CSR build (by destination node). deg must be zeroed beforehand.
// ---------------------------------------------------------------------------
__global__ __launch_bounds__(256) void hist_kernel(const int* __restrict__ end_idx,
                                                   int* __restrict__ deg) {
    int e = blockIdx.x * 256 + threadIdx.x;
    if (e >= N_EDGES) return;
    atomicAdd(&deg[end_idx[e]], 1);
}

__global__ __launch_bounds__(256) void reduce_block_kernel(const int* __restrict__ deg,
                                                           int* __restrict__ blockSums) {
    __shared__ int sh[256];
    int t = threadIdx.x;
    int i = blockIdx.x * 256 + t;
    sh[t] = (i < V_NODES) ? deg[i] : 0;
    __syncthreads();
    for (int s = 128; s > 0; s >>= 1) {
        if (t < s) sh[t] += sh[t + s];
        __syncthreads();
    }
    if (t == 0) blockSums[blockIdx.x] = sh[0];
}

__global__ void scan_sums_kernel(const int* __restrict__ blockSums,
                                 int* __restrict__ blockOffs) {
    if (threadIdx.x == 0) {
        int run = 0;
        for (int i = 0; i < NB_SCAN; ++i) { blockOffs[i] = run; run += blockSums[i]; }
    }
}

// writes BOTH offsets and cursor (avoids a D2D memcpy in the launch)
__global__ __launch_bounds__(256) void scan_block_kernel(const int* __restrict__ deg,
                                                         const int* __restrict__ blockOffs,
                                                         int* __restrict__ offsets,
                                                         int* __restrict__ cursor) {
    __shared__ int sh[256];
    int t = threadIdx.x;
    int i = blockIdx.x * 256 + t;
    int v = (i < V_NODES) ? deg[i] : 0;
    sh[t] = v;
    __syncthreads();
    int run = v;
    for (int ofs = 1; ofs < 256; ofs <<= 1) {
        int add = (t >= ofs) ? sh[t - ofs] : 0;
        __syncthreads();
        run += add;
        sh[t] = run;
        __syncthreads();
    }
    if (i < V_NODES) {
        int o = run - v + blockOffs[blockIdx.x];
        offsets[i] = o;
        cursor[i] = o;
    }
}

// edge_src[p] = start node, grouped by dst
__global__ __launch_bounds__(256) void scatter_kernel(const int* __restrict__ start_idx,
                                                      const int* __restrict__ end_idx,
                                                      int* __restrict__ cursor,
                                                      int* __restrict__ edge_src) {
    int e = blockIdx.x * 256 + threadIdx.x;
    if (e >= N_EDGES) return;
    int d = end_idx[e];
    int p = atomicAdd(&cursor[d], 1);
    edge_src[p] = start_idx[e];
}

// ---------------------------------------------------------------------------
// Repack all 18 weight matrices once into k-inner transposed layout:
//   WTX[m] as float4[k4][j]  (k4 = k/4, j = 0..127), where the float4 holds
//   W[m][j][k4*4 .. k4*4+3].  B-fragments then read as contiguous b128.
// grid (16, 18); one float4 per thread; coalesced stores, 16 B gather reads.
// ---------------------------------------------------------------------------
struct TransArgs { const float* src[18]; };

__global__ __launch_bounds__(256) void transpose_w(TransArgs ta, float* __restrict__ dst) {
    int m = blockIdx.y;
    const float4* __restrict__ src = (const float4*)ta.src[m];   // [j][32 f4]
    float4* __restrict__ d = (float4*)(dst + (size_t)m * 16384); // [k4*128 + j]
    int idx = blockIdx.x * 256 + threadIdx.x;   // 0..4095
    int k4 = idx >> 7;
    int j  = idx & 127;
    d[idx] = src[j * 32 + k4];
}

// ---------------------------------------------------------------------------
// Block-quantum GEMM: out_w = X @ W_w^T (+ bias_w), fp32 VALU.
// One block = one (64-row X tile, weight w, column-half ch) quantum:
//   stage xs[64][132] (33.8 KB, padded) + wsh[32 k4][64 j] float4 (32 KB,
//   k-inner: each float4 = 4 k values of one column) -- ONE barrier --
//   then a barrier-free inner loop with an 8-row x 2-col register tile:
//   per k4: 8x ds_read_b128 A (32-lane dedup, ~free) + 2x b128 B vs 64 FMA
//   => FMA:DS = 6.4:1, above the per-CU DS-pipe balance point (DS is shared
//   per CU, VALU per SIMD: need >= ~6). 65 KB LDS -> 2 blocks/CU; staging of
//   one block overlaps compute of the co-resident one. Grid = 782*nw*2
//   (15 residency rounds -> ~98% tail efficiency). W L2-hot (wch-major grid).
// ---------------------------------------------------------------------------
struct GemmArgs {
    const float* WT[5];
    const float* bias[5];
    float*       out[5];
    int          ldc2[5];   // output row stride in float2 units (64=dense, 128=packed)
    int          nw;
};

__global__ __launch_bounds__(256, 2) void gemm_block(const float* __restrict__ X,
                                                     GemmArgs args) {
    __shared__ float  xs[GB_ROWS][132];      // +4 pad
    __shared__ float4 wsh[32 * 64];          // [k4][j] k-inner half-weight
    const int t = threadIdx.x;
    const int tile = blockIdx.x % GB_NT;
    const int wch  = blockIdx.x / GB_NT;
    const int w  = wch >> 1;
    const int ch = wch & 1;
    const int row0 = tile * GB_ROWS;

    // ---- stage X tile: 64 rows x 32 f4 = 2048 f4, 8/thread, coalesced ----
#pragma unroll
    for (int i = 0; i < 8; ++i) {
        int idx = t + i * 256;               // 0..2047
        int r = idx >> 5;
        int q = idx & 31;
        int rr = row0 + r;
        float4 v = ((const float4*)X)[(size_t)(rr < V_NODES ? rr : V_NODES - 1) * 32 + q];
        *(float4*)&xs[r][q * 4] = v;
    }
    // ---- stage half-weight (k-inner): 2048 f4, 8/thread, coalesced ----
    {
        const float4* __restrict__ wsrc = (const float4*)args.WT[w];
#pragma unroll
        for (int i = 0; i < 8; ++i) {
            int idx = t + i * 256;           // = k4*64 + jq
            int k4 = idx >> 6;
            int jq = idx & 63;
            wsh[idx] = wsrc[k4 * 128 + ch * 64 + jq];
        }
    }
    __syncthreads();

    const int cg = t & 31;                   // cols cg*2, cg*2+1 (of 64)
    const int rg = t >> 5;                   // rows rg*8 .. rg*8+7 (of 64)

    bool ok[8];
#pragma unroll
    for (int i = 0; i < 8; ++i) ok[i] = (row0 + rg * 8 + i) < V_NODES;

    float acc[8][2];
#pragma unroll
    for (int i = 0; i < 8; ++i) { acc[i][0] = 0.f; acc[i][1] = 0.f; }

#pragma unroll 2
    for (int k4 = 0; k4 < 32; ++k4) {
        float4 a[8];
#pragma unroll
        for (int i = 0; i < 8; ++i)
            a[i] = *(const float4*)&xs[rg * 8 + i][k4 * 4];    // 32-lane dedup
        float4 b0 = wsh[k4 * 64 + cg * 2 + 0];                 // col cg*2, k 0..3
        float4 b1 = wsh[k4 * 64 + cg * 2 + 1];                 // col cg*2+1
#pragma unroll
        for (int kk = 0; kk < 4; ++kk) {
            float bb0 = ((const float*)&b0)[kk];
            float bb1 = ((const float*)&b1)[kk];
#pragma unroll
            for (int i = 0; i < 8; ++i) {
                float av = ((const float*)&a[i])[kk];
                acc[i][0] += av * bb0;
                acc[i][1] += av * bb1;
            }
        }
    }

    // ---- epilogue: bias + float2 store (coalesced across cg) ----
    const float* bias = args.bias[w];
    float bb0 = bias ? bias[ch * 64 + cg * 2 + 0] : 0.f;
    float bb1 = bias ? bias[ch * 64 + cg * 2 + 1] : 0.f;
    float2* O = (float2*)args.out[w];
    const int ldc2 = args.ldc2[w];
#pragma unroll
    for (int i = 0; i < 8; ++i) {
        if (ok[i]) {
            float2 o = make_float2(acc[i][0] + bb0, acc[i][1] + bb1);
            O[(size_t)(row0 + rg * 8 + i) * ldc2 + ch * 32 + cg] = o;
        }
    }
}

// ---------------------------------------------------------------------------
// Gather-style aggregation (no atomics), packed source operand.
// P[v] = [ Vjx[v] (128 f32) | Ujx[v] (128 f32) ]  -> one contiguous 1 KB
// region per gathered source node. agg[d] prefilled with Uix[d] + bu.
//   acc = agg[d]; for each in-edge (s -> d):
//     acc += sigmoid(Vix[d] + Vjx[s] + bv) * Ujx[s]
// Block: 256 threads = 8 nodes x 32 lanes (float4 per lane).
// ---------------------------------------------------------------------------
__global__ __launch_bounds__(256) void agg_kernel(const float* __restrict__ Vix,
                                                  const float* __restrict__ P,
                                                  const float* __restrict__ bv,
                                                  const int* __restrict__ offsets,
                                                  const int* __restrict__ deg,
                                                  const int* __restrict__ edge_src,
                                                  float* __restrict__ agg) {
    int t = threadIdx.x;
    int node = blockIdx.x * 8 + (t >> 5);
    int q = t & 31;
    if (node >= V_NODES) return;

    float4 vi  = ((const float4*)Vix)[node * 32 + q];
    float4 bvv = ((const float4*)bv)[q];
    float4 acc = ((const float4*)agg)[node * 32 + q];   // Uix + bu prefill

    int off = offsets[node];
    int dg  = deg[node];
#pragma unroll 2
    for (int i = 0; i < dg; ++i) {
        int s = edge_src[off + i];                      // broadcast across 32 lanes
        const float4* Pr = (const float4*)P + (size_t)s * 64;
        float4 vj = Pr[q];
        float4 uj = Pr[32 + q];
        float g0 = 1.f / (1.f + __expf(-(vi.x + vj.x + bvv.x)));
        float g1 = 1.f / (1.f + __expf(-(vi.y + vj.y + bvv.y)));
        float g2 = 1.f / (1.f + __expf(-(vi.z + vj.z + bvv.z)));
        float g3 = 1.f / (1.f + __expf(-(vi.w + vj.w + bvv.w)));
        acc.x += g0 * uj.x;
        acc.y += g1 * uj.y;
        acc.z += g2 * uj.z;
        acc.w += g3 * uj.w;
    }
    ((float4*)agg)[node * 32 + q] = acc;
}

// ---------------------------------------------------------------------------
// Per-column sum / sum-of-squares over V rows -> stats[0..127]=sum,
// stats[128..255]=sumsq. stats must be zeroed beforehand.
// ---------------------------------------------------------------------------
__global__ __launch_bounds__(256) void bn_stats_kernel(const float* __restrict__ h,
                                                       float* __restrict__ stats) {
    __shared__ float s1[256], s2[256];
    int t = threadIdx.x;
    int j = t & 127;
    int half = t >> 7;
    float sum = 0.f, ss = 0.f;
    for (int r = blockIdx.x * 2 + half; r < V_NODES; r += gridDim.x * 2) {
        float v = h[r * 128 + j];
        sum += v; ss += v * v;
    }
    s1[t] = sum; s2[t] = ss;
    __syncthreads();
    if (t < 128) {
        sum = s1[t] + s1[t + 128];
        ss = s2[t] + s2[t + 128];
        atomicAdd(&stats[j], sum);
        atomicAdd(&stats[128 + j], ss);
    }
}

// ---------------------------------------------------------------------------
// x2 = relu(g*(h-mean)*rsqrt(var+eps)+b)
// ---------------------------------------------------------------------------
__global__ __launch_bounds__(256) void norm_relu_kernel(const float* __restrict__ h,
                                                        const float* __restrict__ stats,
                                                        const float* __restrict__ g,
                                                        const float* __restrict__ b,
                                                        float* __restrict__ out) {
    int idx = blockIdx.x * 256 + threadIdx.x;       // over V*32
    if (idx >= V_NODES * 32) return;
    int q = idx & 31;
    float4 hv = ((const float4*)h)[idx];
    float hvv[4] = {hv.x, hv.y, hv.z, hv.w};
    const float invV = 1.f / (float)V_NODES;
    float o[4];
#pragma unroll
    for (int c = 0; c < 4; ++c) {
        int j = q * 4 + c;
        float m = stats[j] * invV;
        float var = stats[128 + j] * invV - m * m;
        float sc = g[j] * rsqrtf(var + BN_EPS);
        float val = (hvv[c] - m) * sc + b[j];
        o[c] = fmaxf(val, 0.f);
    }
    ((float4*)out)[idx] = make_float4(o[0], o[1], o[2], o[3]);
}

// x3 = relu(bn(h) + rx)
__global__ __launch_bounds__(256) void norm_res_relu_kernel(const float* __restrict__ h,
                                                            const float* __restrict__ stats,
                                                            const float* __restrict__ g,
                                                            const float* __restrict__ b,
                                                            const float* __restrict__ rx,
                                                            float* __restrict__ out) {
    int idx = blockIdx.x * 256 + threadIdx.x;
    if (idx >= V_NODES * 32) return;
    int q = idx & 31;
    float4 hv = ((const float4*)h)[idx];
    float4 rv = ((const float4*)rx)[idx];
    float hvv[4] = {hv.x, hv.y, hv.z, hv.w};
    float rvv[4] = {rv.x, rv.y, rv.z, rv.w};
    const float invV = 1.f / (float)V_NODES;
    float o[4];
#pragma unroll
    for (int c = 0; c < 4; ++c) {
        int j = q * 4 + c;
        float m = stats[j] * invV;
        float var = stats[128 + j] * invV - m * m;
        float sc = g[j] * rsqrtf(var + BN_EPS);
        float val = (hvv[c] - m) * sc + b[j] + rvv[c];
        o[c] = fmaxf(val, 0.f);
    }
    ((float4*)out)[idx] = make_float4(o[0], o[1], o[2], o[3]);
}

// ---------------------------------------------------------------------------
// out[v,k] = sum_h x[v,h]*fc_w[k,h] + fc_b[k]    (k=0..9)
// ---------------------------------------------------------------------------
__global__ __launch_bounds__(256) void fc_kernel(const float* __restrict__ X,
                                                 const float* __restrict__ fw,
                                                 const float* __restrict__ fb,
                                                 float* __restrict__ out) {
    __shared__ float fwsh[NCLUST][132];
    __shared__ float fbsh[NCLUST];
    int t = threadIdx.x;
    for (int i = t; i < NCLUST * 128; i += 256) fwsh[i >> 7][i & 127] = fw[i];
    if (t < NCLUST) fbsh[t] = fb[t];
    __syncthreads();
    int rl = t >> 5;
    int q = t & 31;
    int r = blockIdx.x * 8 + rl;
    float4 xv = make_float4(0.f, 0.f, 0.f, 0.f);
    if (r < V_NODES) xv = ((const float4*)X)[r * 32 + q];
    float p[NCLUST];
#pragma unroll
    for (int k = 0; k < NCLUST; ++k) {
        float4 wv = *(const float4*)&fwsh[k][q * 4];
        p[k] = xv.x * wv.x + xv.y * wv.y + xv.z * wv.z + xv.w * wv.w;
    }
#pragma unroll
    for (int off = 16; off > 0; off >>= 1)
#pragma unroll
        for (int k = 0; k < NCLUST; ++k) p[k] += __shfl_down(p[k], off, 32);
    if (q == 0 && r < V_NODES) {
#pragma unroll
        for (int k = 0; k < NCLUST; ++k) out[r * NCLUST + k] = p[k] + fbsh[k];
    }
}

// ---------------------------------------------------------------------------
extern "C" void kernel_launch(void* const* d_in, const int* in_sizes, int n_in,
                              void* d_out, int out_size, void* d_ws, size_t ws_size,
                              hipStream_t stream) {
    (void)in_sizes; (void)n_in; (void)out_size; (void)ws_size;
    const int*   signal    = (const int*)d_in[0];
    const int*   start_idx = (const int*)d_in[1];
    const int*   end_idx   = (const int*)d_in[2];
    const float* emb       = (const float*)d_in[3];
    const float* Ui1 = (const float*)d_in[4];
    const float* Uj1 = (const float*)d_in[5];
    const float* Vi1 = (const float*)d_in[6];
    const float* Vj1 = (const float*)d_in[7];
    const float* Ui2 = (const float*)d_in[8];
    const float* Uj2 = (const float*)d_in[9];
    const float* Vi2 = (const float*)d_in[10];
    const float* Vj2 = (const float*)d_in[11];
    const float* Rw  = (const float*)d_in[12];
    const float* bu1 = (const float*)d_in[13];
    const float* bv1 = (const float*)d_in[14];
    const float* bu2 = (const float*)d_in[15];
    const float* bv2 = (const float*)d_in[16];
    const float* bn1_g = (const float*)d_in[17];
    const float* bn2_g = (const float*)d_in[18];
    const float* bn1_b = (const float*)d_in[19];
    const float* bn2_b = (const float*)d_in[20];
    const float* fc_w  = (const float*)d_in[21];
    const float* fc_b  = (const float*)d_in[22];
    float* out = (float*)d_out;

    // workspace: X, VI, P(2*VH packed Vj|Uj), AGG, RX  = 6*VH f32,
    // + WT (18*16384), + stats, + CSR int arrays
    const size_t VH = (size_t)V_NODES * H_DIM;
    float* ws  = (float*)d_ws;
    float* X   = ws + 0 * VH;
    float* VI  = ws + 1 * VH;
    float* P   = ws + 2 * VH;   // packed [V][256]: Vjx | Ujx
    float* AGG = ws + 4 * VH;   // Uix + bu, then += gathered messages
    float* RX  = ws + 5 * VH;
    float* stats = ws + 6 * VH;                 // 4 x 256 floats
    float* WT    = stats + 4 * 256;             // 18 matrices, k-inner transposed
    int* ip        = (int*)(WT + 18 * 16384);
    int* deg       = ip;                        // V
    int* offsets   = ip + V_NODES;              // V
    int* cursor    = ip + 2 * V_NODES;          // V
    int* blockSums = ip + 3 * V_NODES;          // NB_SCAN
    int* blockOffs = blockSums + NB_SCAN;       // NB_SCAN
    int* edge_src  = blockOffs + NB_SCAN;       // N_EDGES

    hipMemsetAsync(stats, 0, 4 * 256 * sizeof(float), stream);
    hipMemsetAsync(deg, 0, V_NODES * sizeof(int), stream);

    const int vec_grid  = (V_NODES * 32 + 255) / 256;   // 6250
    const int edge_grid = (N_EDGES + 255) / 256;        // 1954
    const int node_grid = (V_NODES + 7) / 8;            // 6250

    // ---- repack all 18 weight matrices once (k-inner transposed) ----
    // slot order per cell c: [0]=Vi1 [1]=Vj1 [2]=Uj1 [3]=Ui1 [4]=R
    //                        [5]=Vi2 [6]=Vj2 [7]=Uj2 [8]=Ui2
    TransArgs ta;
    for (int c = 0; c < 2; ++c) {
        const int wo = c * H_DIM * H_DIM;
        ta.src[c * 9 + 0] = Vi1 + wo;
        ta.src[c * 9 + 1] = Vj1 + wo;
        ta.src[c * 9 + 2] = Uj1 + wo;
        ta.src[c * 9 + 3] = Ui1 + wo;
        ta.src[c * 9 + 4] = Rw  + wo;
        ta.src[c * 9 + 5] = Vi2 + wo;
        ta.src[c * 9 + 6] = Vj2 + wo;
        ta.src[c * 9 + 7] = Uj2 + wo;
        ta.src[c * 9 + 8] = Ui2 + wo;
    }
    transpose_w<<<dim3(16, 18), 256, 0, stream>>>(ta, WT);

    // ---- CSR build (end_idx is the same for both cells) ----
    hist_kernel<<<edge_grid, 256, 0, stream>>>(end_idx, deg);
    reduce_block_kernel<<<NB_SCAN, 256, 0, stream>>>(deg, blockSums);
    scan_sums_kernel<<<1, 64, 0, stream>>>(blockSums, blockOffs);
    scan_block_kernel<<<NB_SCAN, 256, 0, stream>>>(deg, blockOffs, offsets, cursor);
    scatter_kernel<<<edge_grid, 256, 0, stream>>>(start_idx, end_idx, cursor, edge_src);

    embed_kernel<<<vec_grid, 256, 0, stream>>>(signal, emb, X);

    for (int c = 0; c < 2; ++c) {
        const int bo = c * H_DIM;
        float* WTc = WT + (size_t)c * 9 * 16384;

        // ---- half-cell 1: Vi, Vj->P, Uj->P+128, Ui->AGG(+bu), R->RX ----
        GemmArgs g1;
        g1.WT[0] = WTc + 0 * 16384; g1.bias[0] = nullptr;  g1.out[0] = VI;      g1.ldc2[0] = 64;
        g1.WT[1] = WTc + 1 * 16384; g1.bias[1] = nullptr;  g1.out[1] = P;       g1.ldc2[1] = 128;
        g1.WT[2] = WTc + 2 * 16384; g1.bias[2] = nullptr;  g1.out[2] = P + 128; g1.ldc2[2] = 128;
        g1.WT[3] = WTc + 3 * 16384; g1.bias[3] = bu1 + bo; g1.out[3] = AGG;     g1.ldc2[3] = 64;
        g1.WT[4] = WTc + 4 * 16384; g1.bias[4] = nullptr;  g1.out[4] = RX;      g1.ldc2[4] = 64;
        g1.nw = 5;
        gemm_block<<<GB_NT * 10, 256, 0, stream>>>(X, g1);
        agg_kernel<<<node_grid, 256, 0, stream>>>(VI, P, bv1 + bo,
                                                  offsets, deg, edge_src, AGG);
        bn_stats_kernel<<<1024, 256, 0, stream>>>(AGG, stats + c * 512);
        norm_relu_kernel<<<vec_grid, 256, 0, stream>>>(AGG, stats + c * 512,
                                                       bn1_g + bo, bn1_b + bo, X);

        // ---- half-cell 2 ----
        GemmArgs g2;
        g2.WT[0] = WTc + 5 * 16384; g2.bias[0] = nullptr;  g2.out[0] = VI;      g2.ldc2[0] = 64;
        g2.WT[1] = WTc + 6 * 16384; g2.bias[1] = nullptr;  g2.out[1] = P;       g2.ldc2[1] = 128;
        g2.WT[2] = WTc + 7 * 16384; g2.bias[2] = nullptr;  g2.out[2] = P + 128; g2.ldc2[2] = 128;
        g2.WT[3] = WTc + 8 * 16384; g2.bias[3] = bu2 + bo; g2.out[3] = AGG;     g2.ldc2[3] = 64;
        g2.nw = 4;
        gemm_block<<<GB_NT * 8, 256, 0, stream>>>(X, g2);
        agg_kernel<<<node_grid, 256, 0, stream>>>(VI, P, bv2 + bo,
                                                  offsets, deg, edge_src, AGG);
        bn_stats_kernel<<<1024, 256, 0, stream>>>(AGG, stats + c * 512 + 256);
        norm_res_relu_kernel<<<vec_grid, 256, 0, stream>>>(AGG, stats + c * 512 + 256,
                                                           bn2_g + bo, bn2_b + bo,
                                                           RX, X);
    }

    fc_kernel<<<(V_NODES + 7) / 8, 256, 0, stream>>>(X, fc_w, fc_b, out);
}